// Round 2
// baseline (2253.108 us; speedup 1.0000x reference)
//
#include <hip/hip_runtime.h>
#include <math.h>

// Problem constants (DeformConv_68109591380935) — ALL TENSORS FLOAT32
#define BN_    4
#define CHI_   256
#define CHO_   256
#define HH_    96
#define WW_    96
#define HW_    (HH_*WW_)        // 9216
#define KK_    9
#define CK_    (CHI_*KK_)       // 2304
#define PIX_   16               // pixels per block tile (96 % 16 == 0 -> no row straddle)
#define QJ_    (CK_/4)          // 576, K split in quarters: LDS = 576*16*4 = 36 KB
#define NRED_  (BN_*HW_)        // 36864 samples per BN channel
#define BN_EPS_ 1e-5f

// ---------------------------------------------------------------------------
// Kernel 1: offset conv  om[b, oc(27), h, w] = conv3x3(x, w_offset) + b_offset
// f32, one thread per output element. Consecutive threads = consecutive pixels
// (coalesced x loads); oc uniform per block (scalar w loads).
// ---------------------------------------------------------------------------
__global__ __launch_bounds__(256) void offset_conv(
    const float* __restrict__ x, const float* __restrict__ wo,
    const float* __restrict__ bo, float* __restrict__ om)
{
    int idx = blockIdx.x * 256 + threadIdx.x;          // < 4*27*9216 = 995328
    int p   = idx % HW_;
    int boc = idx / HW_;
    int oc  = boc % 27;
    int b   = boc / 27;
    int h = p / WW_, w = p % WW_;

    int   offs[9];
    float msk[9];
#pragma unroll
    for (int k = 0; k < 9; k++) {
        int yy = h + k / 3 - 1, xx = w + k % 3 - 1;
        bool ok = ((unsigned)yy < HH_) & ((unsigned)xx < WW_);
        offs[k] = ok ? (yy * WW_ + xx) : 0;
        msk[k]  = ok ? 1.f : 0.f;
    }
    const float* xb = x  + (size_t)b * CHI_ * HW_;
    const float* wr = wo + (size_t)oc * CK_;
    float acc = bo[oc];
    for (int c = 0; c < CHI_; c++) {
        const float* xc = xb + c * HW_;
        const float* wc = wr + c * 9;
#pragma unroll
        for (int k = 0; k < 9; k++)
            acc += msk[k] * xc[offs[k]] * wc[k];
    }
    om[idx] = acc;
}

// ---------------------------------------------------------------------------
// Kernel 2: deformable gather + 256x2304 "GEMM", tile = 16 pixels x 256 oc.
// cols staged in LDS in 4 K-quarters (36 KB each). Thread t = output channel.
// LDS reads in the compute loop are wave-broadcast (same address all lanes).
// ---------------------------------------------------------------------------
__global__ __launch_bounds__(256) void deform_main(
    const float* __restrict__ x, const float* __restrict__ om,
    const float* __restrict__ wconv, const float* __restrict__ bconv,
    float* __restrict__ outb)
{
    __shared__ __align__(16) float s_cols[QJ_ * PIX_];   // 36 KB
    __shared__ float s_py[KK_ * PIX_], s_px[KK_ * PIX_], s_mask[KK_ * PIX_];

    int t    = threadIdx.x;
    int tile = blockIdx.x % (HW_ / PIX_);   // 576
    int b    = blockIdx.x / (HW_ / PIX_);
    int p0   = tile * PIX_;
    int h = p0 / WW_, w0 = p0 % WW_;

    if (t < KK_ * PIX_) {                    // 144 threads
        int k = t / PIX_, i = t % PIX_;
        const float* omb = om + ((size_t)b * 27) * HW_ + (p0 + i);
        float dy = omb[(2 * k) * HW_];
        float dx = omb[(2 * k + 1) * HW_];
        float m  = omb[(18 + k) * HW_];
        s_py[t]   = dy + (float)(h + k / 3 - 1);
        s_px[t]   = dx + (float)(w0 + i + (k % 3) - 1);
        s_mask[t] = 1.f / (1.f + __expf(-m));
    }
    __syncthreads();

    float acc[PIX_];
#pragma unroll
    for (int i = 0; i < PIX_; i++) acc[i] = 0.f;

    const float* xb = x + (size_t)b * CHI_ * HW_;

    for (int q = 0; q < 4; q++) {
        if (q) __syncthreads();  // protect s_cols before overwrite
        // ---- stage: bilinear-gather this K-quarter into LDS ----
        for (int e = t; e < QJ_ * PIX_; e += 256) {
            int jl = e >> 4, i = e & 15;
            int jg = jl + q * QJ_;                // 0..2303
            int c  = (jg * 7282) >> 16;           // jg/9 (exact for jg<2304)
            int k  = jg - 9 * c;
            float py = s_py[k * PIX_ + i], px = s_px[k * PIX_ + i];
            float y0f = floorf(py), x0f = floorf(px);
            float ly = py - y0f, lx = px - x0f;
            int y0 = (int)y0f, x0 = (int)x0f;
            float vy0 = ((unsigned)y0       < HH_) ? 1.f : 0.f;
            float vy1 = ((unsigned)(y0 + 1) < HH_) ? 1.f : 0.f;
            float vx0 = ((unsigned)x0       < WW_) ? 1.f : 0.f;
            float vx1 = ((unsigned)(x0 + 1) < WW_) ? 1.f : 0.f;
            int yc0 = min(max(y0, 0), HH_ - 1), yc1 = min(max(y0 + 1, 0), HH_ - 1);
            int xc0 = min(max(x0, 0), WW_ - 1), xc1 = min(max(x0 + 1, 0), WW_ - 1);
            const float* img = xb + (size_t)c * HW_;
            float f00 = img[yc0 * WW_ + xc0];
            float f01 = img[yc0 * WW_ + xc1];
            float f10 = img[yc1 * WW_ + xc0];
            float f11 = img[yc1 * WW_ + xc1];
            float wy0 = 1.f - ly, wx0 = 1.f - lx;
            float v = f00 * (wy0 * wx0 * vy0 * vx0) + f01 * (wy0 * lx * vy0 * vx1)
                    + f10 * (ly  * wx0 * vy1 * vx0) + f11 * (ly  * lx * vy1 * vx1);
            s_cols[e] = v * s_mask[k * PIX_ + i];
        }
        __syncthreads();
        // ---- compute: thread t = output channel, 16 pixels, 4 j per group ----
        const float4* wq = reinterpret_cast<const float4*>(
            wconv + (size_t)t * CK_ + q * QJ_);
#pragma unroll 1
        for (int g = 0; g < QJ_ / 4; g++) {      // 144 groups
            float4 wv = wq[g];
            const float* cr = s_cols + g * 4 * PIX_;
            float wf[4] = {wv.x, wv.y, wv.z, wv.w};
#pragma unroll
            for (int s = 0; s < 4; s++) {
                const float* c0 = cr + s * PIX_;
                float4 a = *reinterpret_cast<const float4*>(c0);
                float4 bq = *reinterpret_cast<const float4*>(c0 + 4);
                float4 cq = *reinterpret_cast<const float4*>(c0 + 8);
                float4 dq = *reinterpret_cast<const float4*>(c0 + 12);
                acc[0]  += wf[s] * a.x;  acc[1]  += wf[s] * a.y;
                acc[2]  += wf[s] * a.z;  acc[3]  += wf[s] * a.w;
                acc[4]  += wf[s] * bq.x; acc[5]  += wf[s] * bq.y;
                acc[6]  += wf[s] * bq.z; acc[7]  += wf[s] * bq.w;
                acc[8]  += wf[s] * cq.x; acc[9]  += wf[s] * cq.y;
                acc[10] += wf[s] * cq.z; acc[11] += wf[s] * cq.w;
                acc[12] += wf[s] * dq.x; acc[13] += wf[s] * dq.y;
                acc[14] += wf[s] * dq.z; acc[15] += wf[s] * dq.w;
            }
        }
    }

    float bc = bconv[t];
    float* orow = outb + ((size_t)b * CHO_ + t) * HW_ + p0;
#pragma unroll
    for (int v = 0; v < 4; v++) {
        float4 st;
        st.x = acc[4 * v]     + bc;
        st.y = acc[4 * v + 1] + bc;
        st.z = acc[4 * v + 2] + bc;
        st.w = acc[4 * v + 3] + bc;
        *reinterpret_cast<float4*>(orow + 4 * v) = st;
    }
}

// ---------------------------------------------------------------------------
// Kernel 3: BN statistics (sum, sumsq) per channel, deterministic two-pass
// ---------------------------------------------------------------------------
__global__ __launch_bounds__(256) void bn_stats(
    const float* __restrict__ outb, float* __restrict__ stats)
{
    int o = blockIdx.x, t = threadIdx.x;
    float s = 0.f, s2 = 0.f;
    for (int b = 0; b < BN_; b++) {
        const float* base = outb + ((size_t)b * CHO_ + o) * HW_;
        for (int p = t; p < HW_; p += 256) {
            float v = base[p];
            s += v; s2 += v * v;
        }
    }
#pragma unroll
    for (int off = 32; off > 0; off >>= 1) {
        s  += __shfl_down(s,  off, 64);
        s2 += __shfl_down(s2, off, 64);
    }
    __shared__ float rs[4], rs2[4];
    int lane = t & 63, wv = t >> 6;
    if (lane == 0) { rs[wv] = s; rs2[wv] = s2; }
    __syncthreads();
    if (t == 0) {
        stats[o]        = rs[0] + rs[1] + rs[2] + rs[3];
        stats[CHO_ + o] = rs2[0] + rs2[1] + rs2[2] + rs2[3];
    }
}

// ---------------------------------------------------------------------------
// Kernel 4: BN apply + ReLU, f32 out
// ---------------------------------------------------------------------------
__global__ __launch_bounds__(256) void bn_apply(
    const float* __restrict__ outb, const float* __restrict__ stats,
    const float* __restrict__ gamma, const float* __restrict__ beta,
    float* __restrict__ y)
{
    int idx = blockIdx.x * 256 + threadIdx.x;
    size_t i0 = (size_t)idx * 4;                  // < 9437184
    int o = (int)((i0 / HW_) % CHO_);
    float4 v = *reinterpret_cast<const float4*>(outb + i0);
    const float invN = 1.f / (float)NRED_;
    float mu  = stats[o] * invN;
    float var = stats[CHO_ + o] * invN - mu * mu;
    float inv = rsqrtf(var + BN_EPS_);
    float sc = gamma[o] * inv;
    float sh = beta[o] - mu * sc;
    float4 r;
    r.x = fmaxf(v.x * sc + sh, 0.f);
    r.y = fmaxf(v.y * sc + sh, 0.f);
    r.z = fmaxf(v.z * sc + sh, 0.f);
    r.w = fmaxf(v.w * sc + sh, 0.f);
    *reinterpret_cast<float4*>(y + i0) = r;
}

// ---------------------------------------------------------------------------
extern "C" void kernel_launch(void* const* d_in, const int* in_sizes, int n_in,
                              void* d_out, int out_size, void* d_ws, size_t ws_size,
                              hipStream_t stream)
{
    const float* x   = (const float*)d_in[0];
    const float* wof = (const float*)d_in[1];
    const float* bof = (const float*)d_in[2];
    const float* wcv = (const float*)d_in[3];
    const float* bcv = (const float*)d_in[4];
    const float* gam = (const float*)d_in[5];
    const float* bet = (const float*)d_in[6];
    float* y = (float*)d_out;

    char* ws = (char*)d_ws;
    float* om    = (float*)ws;                                   // 995328 f32 (~3.98 MB)
    float* outb  = (float*)(ws + (size_t)4 * 1024 * 1024);       // 9437184 f32 (36 MB)
    float* stats = (float*)(ws + (size_t)42 * 1024 * 1024);      // 512 f32

    offset_conv<<<(BN_ * 27 * HW_) / 256, 256, 0, stream>>>(x, wof, bof, om);
    deform_main<<<BN_ * (HW_ / PIX_), 256, 0, stream>>>(x, om, wcv, bcv, outb);
    bn_stats<<<CHO_, 256, 0, stream>>>(outb, stats);
    bn_apply<<<(BN_ * CHO_ * HW_) / (4 * 256), 256, 0, stream>>>(outb, stats, gam, bet, y);
}

// Round 4
// 1389.530 us; speedup vs baseline: 1.6215x; 1.6215x over previous
//
#include <hip/hip_runtime.h>
#include <math.h>

// Problem constants (DeformConv_68109591380935) — ALL TENSORS FLOAT32
#define BN_    4
#define CHI_   256
#define CHO_   256
#define HH_    96
#define WW_    96
#define HW_    (HH_*WW_)        // 9216
#define KK_    9
#define CK_    (CHI_*KK_)       // 2304
#define NRED_  (BN_*HW_)        // 36864 samples per BN channel
#define BN_EPS_ 1e-5f

// MFMA deform_main tiling
#define TOC_   128              // oc per block
#define TPX_   64               // pixels per block
#define KC_    96               // K-chunk staged in LDS (3 x 32)
#define PITCH_ 104              // LDS row pitch in bf16 (96 + 8 pad; 208B rows, 16B-aligned, 2-way banks free)

typedef short short8 __attribute__((ext_vector_type(8)));
typedef float f32x4  __attribute__((ext_vector_type(4)));

// round-to-nearest-even f32 -> bf16 (bit pattern as ushort); no hip_bf16.h needed
__device__ __forceinline__ unsigned short f2bf(float v) {
    union { float f; unsigned u; } c; c.f = v;
    unsigned lsb = (c.u >> 16) & 1u;
    c.u += 0x7fffu + lsb;
    return (unsigned short)(c.u >> 16);
}

// ---------------------------------------------------------------------------
// Kernel 0: convert w_conv f32 -> bf16 (row-major [oc][2304])
// ---------------------------------------------------------------------------
__global__ __launch_bounds__(256) void w2b(
    const float* __restrict__ w, unsigned short* __restrict__ wb)
{
    int idx = blockIdx.x * 256 + threadIdx.x;   // < 589824
    wb[idx] = f2bf(w[idx]);
}

// ---------------------------------------------------------------------------
// Kernel 1: offset conv  om[b, oc(27), h, w] = conv3x3(x, w_offset) + b_offset
// ---------------------------------------------------------------------------
__global__ __launch_bounds__(256) void offset_conv(
    const float* __restrict__ x, const float* __restrict__ wo,
    const float* __restrict__ bo, float* __restrict__ om)
{
    int idx = blockIdx.x * 256 + threadIdx.x;          // < 4*27*9216 = 995328
    int p   = idx % HW_;
    int boc = idx / HW_;
    int oc  = boc % 27;
    int b   = boc / 27;
    int h = p / WW_, w = p % WW_;

    int   offs[9];
    float msk[9];
#pragma unroll
    for (int k = 0; k < 9; k++) {
        int yy = h + k / 3 - 1, xx = w + k % 3 - 1;
        bool ok = ((unsigned)yy < HH_) & ((unsigned)xx < WW_);
        offs[k] = ok ? (yy * WW_ + xx) : 0;
        msk[k]  = ok ? 1.f : 0.f;
    }
    const float* xb = x  + (size_t)b * CHI_ * HW_;
    const float* wr = wo + (size_t)oc * CK_;
    float acc = bo[oc];
    for (int c = 0; c < CHI_; c++) {
        const float* xc = xb + c * HW_;
        const float* wc = wr + c * 9;
#pragma unroll
        for (int k = 0; k < 9; k++)
            acc += msk[k] * xc[offs[k]] * wc[k];
    }
    om[idx] = acc;
}

// ---------------------------------------------------------------------------
// Kernel 2: fused deformable gather + bf16 MFMA GEMM
//   out[128 oc x 64 pix per block] = W[128, 2304] x cols[2304, 64]
//   4 waves, each a 64x32 register tile = 4x2 MFMA 16x16x32_bf16 tiles.
// ---------------------------------------------------------------------------
__global__ __launch_bounds__(256) void deform_main(
    const float* __restrict__ x, const float* __restrict__ om,
    const unsigned short* __restrict__ wb, const float* __restrict__ bconv,
    float* __restrict__ outb)
{
    __shared__ __align__(16) unsigned short s_w[TOC_ * PITCH_];    // 26624 B
    __shared__ __align__(16) unsigned short s_cols[TPX_ * PITCH_]; // 13312 B
    __shared__ float s_py[KK_ * TPX_], s_px[KK_ * TPX_], s_mask[KK_ * TPX_]; // 6912 B

    const int t = threadIdx.x;
    const int pixtile = blockIdx.x % (HW_ / TPX_);   // 144
    const int rest    = blockIdx.x / (HW_ / TPX_);
    const int octile  = rest % (CHO_ / TOC_);        // 2
    const int b       = rest / (CHO_ / TOC_);        // 4
    const int p0  = pixtile * TPX_;
    const int oc0 = octile * TOC_;

    // ---- meta: py/px/mask for 9 taps x 64 pixels ----
    for (int e = t; e < KK_ * TPX_; e += 256) {
        int k = e / TPX_, i = e % TPX_;
        int p = p0 + i;
        int h = p / WW_, w = p % WW_;
        const float* omb = om + ((size_t)b * 27) * HW_ + p;
        float dy = omb[(2 * k) * HW_];
        float dx = omb[(2 * k + 1) * HW_];
        float m  = omb[(18 + k) * HW_];
        s_py[e]   = dy + (float)(h + k / 3 - 1);
        s_px[e]   = dx + (float)(w + (k % 3) - 1);
        s_mask[e] = 1.f / (1.f + __expf(-m));
    }

    const int lane = t & 63, wave = t >> 6;
    const int quad = lane >> 4, l15 = lane & 15;
    const int ocbase  = (wave >> 1) * 64;   // 0 or 64
    const int pixbase = (wave & 1) * 32;    // 0 or 32

    f32x4 acc[4][2];
#pragma unroll
    for (int m = 0; m < 4; m++)
#pragma unroll
        for (int n = 0; n < 2; n++)
            acc[m][n] = (f32x4){0.f, 0.f, 0.f, 0.f};

    const float* xb = x + (size_t)b * CHI_ * HW_;
    const unsigned short* wrow = wb + (size_t)oc0 * CK_;

    __syncthreads();   // meta visible

    for (int kc = 0; kc < CK_ / KC_; kc++) {       // 24 chunks
        const int j0 = kc * KC_;
        if (kc) __syncthreads();                   // prev compute done
        // ---- stage W chunk: 128 oc x 96 k (as 4-bf16 quads) ----
        for (int e = t; e < TOC_ * (KC_ / 4); e += 256) {   // 3072
            int ocl = e / (KC_ / 4), kq = e % (KC_ / 4);
            const uint2* src = reinterpret_cast<const uint2*>(
                wrow + (size_t)ocl * CK_ + j0 + kq * 4);
            *reinterpret_cast<uint2*>(&s_w[ocl * PITCH_ + kq * 4]) = *src;
        }
        // ---- stage cols chunk: 96 k x 64 pix, bilinear gather ----
        for (int e = t; e < KC_ * TPX_; e += 256) {         // 6144
            int jl = e >> 6, i = e & 63;
            int jg = j0 + jl;
            int c  = (jg * 7282) >> 16;           // jg/9
            int k  = jg - 9 * c;
            float py = s_py[k * TPX_ + i], px = s_px[k * TPX_ + i];
            float y0f = floorf(py), x0f = floorf(px);
            float ly = py - y0f, lx = px - x0f;
            int y0 = (int)y0f, x0 = (int)x0f;
            float vy0 = ((unsigned)y0       < HH_) ? 1.f : 0.f;
            float vy1 = ((unsigned)(y0 + 1) < HH_) ? 1.f : 0.f;
            float vx0 = ((unsigned)x0       < WW_) ? 1.f : 0.f;
            float vx1 = ((unsigned)(x0 + 1) < WW_) ? 1.f : 0.f;
            int yc0 = min(max(y0, 0), HH_ - 1), yc1 = min(max(y0 + 1, 0), HH_ - 1);
            int xc0 = min(max(x0, 0), WW_ - 1), xc1 = min(max(x0 + 1, 0), WW_ - 1);
            const float* img = xb + (size_t)c * HW_;
            float f00 = img[yc0 * WW_ + xc0];
            float f01 = img[yc0 * WW_ + xc1];
            float f10 = img[yc1 * WW_ + xc0];
            float f11 = img[yc1 * WW_ + xc1];
            float wy0 = 1.f - ly, wx0 = 1.f - lx;
            float v = f00 * (wy0 * wx0 * vy0 * vx0) + f01 * (wy0 * lx * vy0 * vx1)
                    + f10 * (ly  * wx0 * vy1 * vx0) + f11 * (ly  * lx * vy1 * vx1);
            s_cols[i * PITCH_ + jl] = f2bf(v * s_mask[k * TPX_ + i]);
        }
        __syncthreads();
        // ---- MFMA compute: 3 K-steps of 32 ----
#pragma unroll
        for (int ks = 0; ks < KC_ / 32; ks++) {
            short8 afr[4], bfr[2];
#pragma unroll
            for (int m = 0; m < 4; m++)
                afr[m] = *reinterpret_cast<const short8*>(
                    &s_w[(ocbase + m * 16 + l15) * PITCH_ + ks * 32 + quad * 8]);
#pragma unroll
            for (int n = 0; n < 2; n++)
                bfr[n] = *reinterpret_cast<const short8*>(
                    &s_cols[(pixbase + n * 16 + l15) * PITCH_ + ks * 32 + quad * 8]);
#pragma unroll
            for (int m = 0; m < 4; m++)
#pragma unroll
                for (int n = 0; n < 2; n++)
                    acc[m][n] = __builtin_amdgcn_mfma_f32_16x16x32_bf16(
                        afr[m], bfr[n], acc[m][n], 0, 0, 0);
        }
    }

    // ---- epilogue: C/D layout col=lane&15, row=quad*4+reg ----
#pragma unroll
    for (int m = 0; m < 4; m++) {
#pragma unroll
        for (int n = 0; n < 2; n++) {
#pragma unroll
            for (int r = 0; r < 4; r++) {
                int oc  = oc0 + ocbase + m * 16 + quad * 4 + r;
                int pix = p0 + pixbase + n * 16 + l15;
                outb[((size_t)b * CHO_ + oc) * HW_ + pix] = acc[m][n][r] + bconv[oc];
            }
        }
    }
}

// ---------------------------------------------------------------------------
// Kernel 3: BN statistics (sum, sumsq) per channel, deterministic two-pass
// ---------------------------------------------------------------------------
__global__ __launch_bounds__(256) void bn_stats(
    const float* __restrict__ outb, float* __restrict__ stats)
{
    int o = blockIdx.x, t = threadIdx.x;
    float s = 0.f, s2 = 0.f;
    for (int b = 0; b < BN_; b++) {
        const float* base = outb + ((size_t)b * CHO_ + o) * HW_;
        for (int p = t; p < HW_; p += 256) {
            float v = base[p];
            s += v; s2 += v * v;
        }
    }
#pragma unroll
    for (int off = 32; off > 0; off >>= 1) {
        s  += __shfl_down(s,  off, 64);
        s2 += __shfl_down(s2, off, 64);
    }
    __shared__ float rs[4], rs2[4];
    int lane = t & 63, wv = t >> 6;
    if (lane == 0) { rs[wv] = s; rs2[wv] = s2; }
    __syncthreads();
    if (t == 0) {
        stats[o]        = rs[0] + rs[1] + rs[2] + rs[3];
        stats[CHO_ + o] = rs2[0] + rs2[1] + rs2[2] + rs2[3];
    }
}

// ---------------------------------------------------------------------------
// Kernel 4: BN apply + ReLU, f32 out
// ---------------------------------------------------------------------------
__global__ __launch_bounds__(256) void bn_apply(
    const float* __restrict__ outb, const float* __restrict__ stats,
    const float* __restrict__ gamma, const float* __restrict__ beta,
    float* __restrict__ y)
{
    int idx = blockIdx.x * 256 + threadIdx.x;
    size_t i0 = (size_t)idx * 4;                  // < 9437184
    int o = (int)((i0 / HW_) % CHO_);
    float4 v = *reinterpret_cast<const float4*>(outb + i0);
    const float invN = 1.f / (float)NRED_;
    float mu  = stats[o] * invN;
    float var = stats[CHO_ + o] * invN - mu * mu;
    float inv = rsqrtf(var + BN_EPS_);
    float sc = gamma[o] * inv;
    float sh = beta[o] - mu * sc;
    float4 r;
    r.x = fmaxf(v.x * sc + sh, 0.f);
    r.y = fmaxf(v.y * sc + sh, 0.f);
    r.z = fmaxf(v.z * sc + sh, 0.f);
    r.w = fmaxf(v.w * sc + sh, 0.f);
    *reinterpret_cast<float4*>(y + i0) = r;
}

// ---------------------------------------------------------------------------
extern "C" void kernel_launch(void* const* d_in, const int* in_sizes, int n_in,
                              void* d_out, int out_size, void* d_ws, size_t ws_size,
                              hipStream_t stream)
{
    const float* x   = (const float*)d_in[0];
    const float* wof = (const float*)d_in[1];
    const float* bof = (const float*)d_in[2];
    const float* wcv = (const float*)d_in[3];
    const float* bcv = (const float*)d_in[4];
    const float* gam = (const float*)d_in[5];
    const float* bet = (const float*)d_in[6];
    float* y = (float*)d_out;

    char* ws = (char*)d_ws;
    float*          om    = (float*)ws;                                 // 3.98 MB
    float*          outb  = (float*)(ws + (size_t)4  * 1024 * 1024);    // 36 MB
    float*          stats = (float*)(ws + (size_t)41 * 1024 * 1024);    // 2 KB
    unsigned short* wbf   = (unsigned short*)(ws + (size_t)42 * 1024 * 1024); // 1.18 MB

    w2b<<<(CHO_ * CK_) / 256, 256, 0, stream>>>(wcv, wbf);
    offset_conv<<<(BN_ * 27 * HW_) / 256, 256, 0, stream>>>(x, wof, bof, om);
    deform_main<<<BN_ * (CHO_ / TOC_) * (HW_ / TPX_), 256, 0, stream>>>(
        x, om, wbf, bcv, outb);
    bn_stats<<<CHO_, 256, 0, stream>>>(outb, stats);
    bn_apply<<<(BN_ * CHO_ * HW_) / (4 * 256), 256, 0, stream>>>(outb, stats, gam, bet, y);
}

// Round 5
// 588.773 us; speedup vs baseline: 3.8268x; 2.3600x over previous
//
#include <hip/hip_runtime.h>
#include <math.h>

// Problem constants (DeformConv_68109591380935) — ALL TENSORS FLOAT32
#define BN_    4
#define CHI_   256
#define CHO_   256
#define HH_    96
#define WW_    96
#define HW_    (HH_*WW_)        // 9216
#define KK_    9
#define CK_    (CHI_*KK_)       // 2304
#define NRED_  (BN_*HW_)        // 36864 samples per BN channel
#define BN_EPS_ 1e-5f

// deform_main tiling: 256 oc x 64 px per block (gather done ONCE per pixel)
#define TPX_   64
#define KC_    64               // K-chunk in LDS
#define PITCH_ 72               // bf16 pitch (64 + 8 pad; 144B rows, 16B aligned)

// offset_mfma tiling: 32 oc (27 + 5 zero) x 64 px, KC 96
#define OKC_    96
#define OPITCH_ 104             // 208B rows (known-good class from R4)

typedef short short8 __attribute__((ext_vector_type(8)));
typedef float f32x4  __attribute__((ext_vector_type(4)));

// round-to-nearest-even f32 -> bf16 bit pattern
__device__ __forceinline__ unsigned short f2bf(float v) {
    union { float f; unsigned u; } c; c.f = v;
    unsigned lsb = (c.u >> 16) & 1u;
    c.u += 0x7fffu + lsb;
    return (unsigned short)(c.u >> 16);
}

// ---------------------------------------------------------------------------
// Kernel 0: f32 -> bf16 convert (used for w_conv and w_offset)
// ---------------------------------------------------------------------------
__global__ __launch_bounds__(256) void w2b(
    const float* __restrict__ w, unsigned short* __restrict__ wb)
{
    int idx = blockIdx.x * 256 + threadIdx.x;
    wb[idx] = f2bf(w[idx]);
}

// ---------------------------------------------------------------------------
// Kernel 1: offset conv as MFMA GEMM.
//   om[b, 27, HW] = Woff[27,2304] x im2col3x3(x)  + b_offset
//   Block: 32 oc (rows 27..31 zero) x 64 px. 4 waves: wave = pixel quarter.
// ---------------------------------------------------------------------------
__global__ __launch_bounds__(256) void offset_mfma(
    const float* __restrict__ x, const unsigned short* __restrict__ wob,
    const float* __restrict__ bo, float* __restrict__ om)
{
    __shared__ __align__(16) unsigned short s_w[32 * OPITCH_];     //  6656 B
    __shared__ __align__(16) unsigned short s_cols[TPX_ * OPITCH_];// 13312 B

    const int t = threadIdx.x;
    const int pixtile = blockIdx.x % (HW_ / TPX_);   // 144
    const int b       = blockIdx.x / (HW_ / TPX_);   // 4
    const int p0 = pixtile * TPX_;

    const int lane = t & 63, wave = t >> 6;
    const int quad = lane >> 4, l15 = lane & 15;

    const int i   = t & 63;            // pixel within tile (staging role)
    const int jlb = (t >> 6) * 24;     // k-subrange within chunk
    const int p   = p0 + i;
    const int h   = p / WW_, w = p % WW_;
    const float* xb = x + (size_t)b * CHI_ * HW_;

    f32x4 acc[2];
    acc[0] = (f32x4){0.f,0.f,0.f,0.f};
    acc[1] = (f32x4){0.f,0.f,0.f,0.f};

    for (int kc = 0; kc < CK_ / OKC_; kc++) {        // 24 chunks
        const int j0 = kc * OKC_;
        if (kc) __syncthreads();
        // ---- stage Woff chunk: 32 x 96 (rows >=27 zero), 3 uint2 per thread
#pragma unroll
        for (int n = 0; n < 3; n++) {
            int e = t + n * 256;                     // < 768
            int ocl = e / 24, kq = e % 24;
            uint2 v = make_uint2(0u, 0u);
            if (ocl < 27)
                v = *reinterpret_cast<const uint2*>(wob + (size_t)ocl * CK_ + j0 + kq * 4);
            *reinterpret_cast<uint2*>(&s_w[ocl * OPITCH_ + kq * 4]) = v;
        }
        // ---- stage im2col chunk: 96 k x 64 px, 24 per thread, 3x b128 write
        union { unsigned short s[24]; uint4 q[3]; } pk;
#pragma unroll
        for (int m = 0; m < 24; m++) {
            int jg = j0 + jlb + m;
            int c  = (jg * 7282) >> 16;              // jg/9
            int k  = jg - 9 * c;
            int yy = h + k / 3 - 1, xx = w + k % 3 - 1;
            bool ok = ((unsigned)yy < HH_) & ((unsigned)xx < WW_);
            float v = ok ? xb[(size_t)c * HW_ + yy * WW_ + xx] : 0.f;
            pk.s[m] = f2bf(v);
        }
        {
            uint4* dst = reinterpret_cast<uint4*>(&s_cols[i * OPITCH_ + jlb]);
            dst[0] = pk.q[0]; dst[1] = pk.q[1]; dst[2] = pk.q[2];
        }
        __syncthreads();
        // ---- MFMA: 3 K-steps, A = 2 oc-tiles, B = this wave's pixel quarter
#pragma unroll
        for (int ks = 0; ks < OKC_ / 32; ks++) {
            short8 a0 = *reinterpret_cast<const short8*>(
                &s_w[(l15) * OPITCH_ + ks * 32 + quad * 8]);
            short8 a1 = *reinterpret_cast<const short8*>(
                &s_w[(16 + l15) * OPITCH_ + ks * 32 + quad * 8]);
            short8 b0 = *reinterpret_cast<const short8*>(
                &s_cols[(wave * 16 + l15) * OPITCH_ + ks * 32 + quad * 8]);
            acc[0] = __builtin_amdgcn_mfma_f32_16x16x32_bf16(a0, b0, acc[0], 0, 0, 0);
            acc[1] = __builtin_amdgcn_mfma_f32_16x16x32_bf16(a1, b0, acc[1], 0, 0, 0);
        }
    }

    // epilogue: C/D layout col=lane&15 (pixel), row=quad*4+r (oc)
#pragma unroll
    for (int mt = 0; mt < 2; mt++) {
#pragma unroll
        for (int r = 0; r < 4; r++) {
            int oc = mt * 16 + quad * 4 + r;
            if (oc < 27) {
                int pix = p0 + wave * 16 + l15;
                om[((size_t)b * 27 + oc) * HW_ + pix] = acc[mt][r] + bo[oc];
            }
        }
    }
}

// ---------------------------------------------------------------------------
// Kernel 2: fused deformable gather + bf16 MFMA GEMM
//   Block: 256 oc x 64 px — gather each col element exactly once.
//   4 waves, each 64 oc x 64 px = 4x4 MFMA tiles.
// ---------------------------------------------------------------------------
__global__ __launch_bounds__(256) void deform_main(
    const float* __restrict__ x, const float* __restrict__ om,
    const unsigned short* __restrict__ wb, const float* __restrict__ bconv,
    float* __restrict__ outb)
{
    __shared__ __align__(16) unsigned short s_w[CHO_ * PITCH_];    // 36864 B
    __shared__ __align__(16) unsigned short s_cols[TPX_ * PITCH_]; //  9216 B
    __shared__ float s_py[KK_ * TPX_], s_px[KK_ * TPX_], s_mask[KK_ * TPX_]; // 6912 B

    const int t = threadIdx.x;
    const int pixtile = blockIdx.x % (HW_ / TPX_);   // 144
    const int b       = blockIdx.x / (HW_ / TPX_);   // 4
    const int p0 = pixtile * TPX_;

    // ---- meta: py/px/mask for 9 taps x 64 pixels ----
    for (int e = t; e < KK_ * TPX_; e += 256) {
        int k = e / TPX_, i = e % TPX_;
        int p = p0 + i;
        int h = p / WW_, w = p % WW_;
        const float* omb = om + ((size_t)b * 27) * HW_ + p;
        float dy = omb[(2 * k) * HW_];
        float dx = omb[(2 * k + 1) * HW_];
        float m  = omb[(18 + k) * HW_];
        s_py[e]   = dy + (float)(h + k / 3 - 1);
        s_px[e]   = dx + (float)(w + (k % 3) - 1);
        s_mask[e] = 1.f / (1.f + __expf(-m));
    }

    const int lane = t & 63, wave = t >> 6;
    const int quad = lane >> 4, l15 = lane & 15;
    const int ib   = t & 63;           // pixel (staging role)
    const int jlb  = (t >> 6) << 4;    // 0,16,32,48

    f32x4 acc[4][4];
#pragma unroll
    for (int m = 0; m < 4; m++)
#pragma unroll
        for (int n = 0; n < 4; n++)
            acc[m][n] = (f32x4){0.f, 0.f, 0.f, 0.f};

    const float* xb = x + (size_t)b * CHI_ * HW_;

    __syncthreads();   // meta visible

    for (int kc = 0; kc < CK_ / KC_; kc++) {       // 36 chunks
        const int j0 = kc * KC_;
        if (kc) __syncthreads();
        // ---- stage W chunk: 256 oc x 64 k, 8 x uint4 per thread ----
#pragma unroll
        for (int n = 0; n < 8; n++) {
            int e = t + n * 256;                   // < 2048
            int ocl = e >> 3, ko = e & 7;
            uint4 v = *reinterpret_cast<const uint4*>(
                wb + (size_t)ocl * CK_ + j0 + ko * 8);
            *reinterpret_cast<uint4*>(&s_w[ocl * PITCH_ + ko * 8]) = v;
        }
        // ---- stage cols: 64 k x 64 px bilinear gather, 16/thread, 2x b128
        union { unsigned short s[16]; uint4 q[2]; } pk;
#pragma unroll
        for (int m = 0; m < 16; m++) {
            int jg = j0 + jlb + m;
            int c  = (jg * 7282) >> 16;           // jg/9
            int k  = jg - 9 * c;
            float py = s_py[k * TPX_ + ib], px = s_px[k * TPX_ + ib];
            float y0f = floorf(py), x0f = floorf(px);
            float ly = py - y0f, lx = px - x0f;
            int y0 = (int)y0f, x0 = (int)x0f;
            float vy0 = ((unsigned)y0       < HH_) ? 1.f : 0.f;
            float vy1 = ((unsigned)(y0 + 1) < HH_) ? 1.f : 0.f;
            float vx0 = ((unsigned)x0       < WW_) ? 1.f : 0.f;
            float vx1 = ((unsigned)(x0 + 1) < WW_) ? 1.f : 0.f;
            int yc0 = min(max(y0, 0), HH_ - 1), yc1 = min(max(y0 + 1, 0), HH_ - 1);
            int xc0 = min(max(x0, 0), WW_ - 1), xc1 = min(max(x0 + 1, 0), WW_ - 1);
            const float* img = xb + (size_t)c * HW_;
            float f00 = img[yc0 * WW_ + xc0];
            float f01 = img[yc0 * WW_ + xc1];
            float f10 = img[yc1 * WW_ + xc0];
            float f11 = img[yc1 * WW_ + xc1];
            float wy0 = 1.f - ly, wx0 = 1.f - lx;
            float v = f00 * (wy0 * wx0 * vy0 * vx0) + f01 * (wy0 * lx * vy0 * vx1)
                    + f10 * (ly  * wx0 * vy1 * vx0) + f11 * (ly  * lx * vy1 * vx1);
            pk.s[m] = f2bf(v * s_mask[k * TPX_ + ib]);
        }
        {
            uint4* dst = reinterpret_cast<uint4*>(&s_cols[ib * PITCH_ + jlb]);
            dst[0] = pk.q[0]; dst[1] = pk.q[1];
        }
        __syncthreads();
        // ---- MFMA: 2 K-steps of 32; wave = 64-oc slice, full 64 px ----
#pragma unroll
        for (int ks = 0; ks < KC_ / 32; ks++) {
            short8 afr[4], bfr[4];
#pragma unroll
            for (int m = 0; m < 4; m++)
                afr[m] = *reinterpret_cast<const short8*>(
                    &s_w[(wave * 64 + m * 16 + l15) * PITCH_ + ks * 32 + quad * 8]);
#pragma unroll
            for (int n = 0; n < 4; n++)
                bfr[n] = *reinterpret_cast<const short8*>(
                    &s_cols[(n * 16 + l15) * PITCH_ + ks * 32 + quad * 8]);
#pragma unroll
            for (int m = 0; m < 4; m++)
#pragma unroll
                for (int n = 0; n < 4; n++)
                    acc[m][n] = __builtin_amdgcn_mfma_f32_16x16x32_bf16(
                        afr[m], bfr[n], acc[m][n], 0, 0, 0);
        }
    }

    // ---- epilogue: C/D layout col=lane&15 (pixel), row=quad*4+r (oc) ----
#pragma unroll
    for (int m = 0; m < 4; m++) {
#pragma unroll
        for (int n = 0; n < 4; n++) {
#pragma unroll
            for (int r = 0; r < 4; r++) {
                int oc  = wave * 64 + m * 16 + quad * 4 + r;
                int pix = p0 + n * 16 + l15;
                outb[((size_t)b * CHO_ + oc) * HW_ + pix] = acc[m][n][r] + bconv[oc];
            }
        }
    }
}

// ---------------------------------------------------------------------------
// Kernel 3: BN statistics (sum, sumsq) per channel, deterministic two-pass
// ---------------------------------------------------------------------------
__global__ __launch_bounds__(256) void bn_stats(
    const float* __restrict__ outb, float* __restrict__ stats)
{
    int o = blockIdx.x, t = threadIdx.x;
    float s = 0.f, s2 = 0.f;
    for (int b = 0; b < BN_; b++) {
        const float* base = outb + ((size_t)b * CHO_ + o) * HW_;
        for (int p = t; p < HW_; p += 256) {
            float v = base[p];
            s += v; s2 += v * v;
        }
    }
#pragma unroll
    for (int off = 32; off > 0; off >>= 1) {
        s  += __shfl_down(s,  off, 64);
        s2 += __shfl_down(s2, off, 64);
    }
    __shared__ float rs[4], rs2[4];
    int lane = t & 63, wv = t >> 6;
    if (lane == 0) { rs[wv] = s; rs2[wv] = s2; }
    __syncthreads();
    if (t == 0) {
        stats[o]        = rs[0] + rs[1] + rs[2] + rs[3];
        stats[CHO_ + o] = rs2[0] + rs2[1] + rs2[2] + rs2[3];
    }
}

// ---------------------------------------------------------------------------
// Kernel 4: BN apply + ReLU, f32 out
// ---------------------------------------------------------------------------
__global__ __launch_bounds__(256) void bn_apply(
    const float* __restrict__ outb, const float* __restrict__ stats,
    const float* __restrict__ gamma, const float* __restrict__ beta,
    float* __restrict__ y)
{
    int idx = blockIdx.x * 256 + threadIdx.x;
    size_t i0 = (size_t)idx * 4;                  // < 9437184
    int o = (int)((i0 / HW_) % CHO_);
    float4 v = *reinterpret_cast<const float4*>(outb + i0);
    const float invN = 1.f / (float)NRED_;
    float mu  = stats[o] * invN;
    float var = stats[CHO_ + o] * invN - mu * mu;
    float inv = rsqrtf(var + BN_EPS_);
    float sc = gamma[o] * inv;
    float sh = beta[o] - mu * sc;
    float4 r;
    r.x = fmaxf(v.x * sc + sh, 0.f);
    r.y = fmaxf(v.y * sc + sh, 0.f);
    r.z = fmaxf(v.z * sc + sh, 0.f);
    r.w = fmaxf(v.w * sc + sh, 0.f);
    *reinterpret_cast<float4*>(y + i0) = r;
}

// ---------------------------------------------------------------------------
extern "C" void kernel_launch(void* const* d_in, const int* in_sizes, int n_in,
                              void* d_out, int out_size, void* d_ws, size_t ws_size,
                              hipStream_t stream)
{
    const float* x   = (const float*)d_in[0];
    const float* wof = (const float*)d_in[1];
    const float* bof = (const float*)d_in[2];
    const float* wcv = (const float*)d_in[3];
    const float* bcv = (const float*)d_in[4];
    const float* gam = (const float*)d_in[5];
    const float* bet = (const float*)d_in[6];
    float* y = (float*)d_out;

    char* ws = (char*)d_ws;
    float*          om    = (float*)ws;                                   // 3.98 MB
    float*          outb  = (float*)(ws + (size_t)4 * 1024 * 1024);       // 36 MB
    float*          stats = (float*)(ws + (size_t)40 * 1024 * 1024);      // 2 KB
    unsigned short* wbf   = (unsigned short*)(ws + (size_t)40 * 1024 * 1024 + 8192);            // 1.125 MB
    unsigned short* wob   = (unsigned short*)(ws + (size_t)40 * 1024 * 1024 + 8192 + 1179648);  // 121.5 KB

    w2b<<<(CHO_ * CK_) / 256, 256, 0, stream>>>(wcv, wbf);        // 2304 blocks
    w2b<<<(27 * CK_) / 256, 256, 0, stream>>>(wof, wob);          // 243 blocks
    offset_mfma<<<BN_ * (HW_ / TPX_), 256, 0, stream>>>(x, wob, bof, om);
    deform_main<<<BN_ * (HW_ / TPX_), 256, 0, stream>>>(x, om, wbf, bcv, outb);
    bn_stats<<<CHO_, 256, 0, stream>>>(outb, stats);
    bn_apply<<<(BN_ * CHO_ * HW_) / (4 * 256), 256, 0, stream>>>(outb, stats, gam, bet, y);
}